// Round 4
// baseline (1404.903 us; speedup 1.0000x reference)
//
#include <hip/hip_runtime.h>
#include <hip/hip_bf16.h>
#include <cstdint>

using bf16 = __hip_bfloat16;
typedef __attribute__((ext_vector_type(8))) short bf16x8;   // MFMA A/B frag (4 VGPRs)
typedef __attribute__((ext_vector_type(4))) float f32x4;    // MFMA C/D frag

#define NB 16
#define NT_ 1024
#define ND 1024
#define NH 4096
#define NM (NB * NT_)   // 16384 rows

enum { EPI_BF16 = 0, EPI_OM, EPI_U, EPI_GELU, EPI_GELU_MUL, EPI_X1, EPI_X2 };

__device__ __forceinline__ float sigm(float x) { return 1.0f / (1.0f + expf(-x)); }
__device__ __forceinline__ float gelu_f(float x) { return 0.5f * x * (1.0f + erff(x * 0.7071067811865476f)); }
__device__ __forceinline__ float b2f(bf16 h) { return __bfloat162float(h); }
__device__ __forceinline__ bf16  f2b(float x) { return __float2bfloat16(x); }

__device__ __forceinline__ void gl_lds16(const bf16* g, void* l) {
  __builtin_amdgcn_global_load_lds((const __attribute__((address_space(1))) void*)g,
                                   (__attribute__((address_space(3))) void*)l, 16, 0, 0);
}

// ---- NT GEMM: C[m,n] = sum_k A[m,k] * Bw[n,k], bf16 in, f32 acc, fused epilogue ----
// 128x128 tile, BK=32, 256 threads (4 waves), wave = 64x64 quadrant of 4x4 16x16x32 MFMAs.
template <int EPI>
__global__ __launch_bounds__(256)
void gemm_nt(const bf16* __restrict__ A, const bf16* __restrict__ Bw,
             int M, int N, int K,
             const float* __restrict__ biasf, const float* __restrict__ vecf,
             const bf16* __restrict__ auxb, const bf16* __restrict__ auxb2,
             const float* __restrict__ auxf,
             float* __restrict__ outf, bf16* __restrict__ outb)
{
  __shared__ __align__(16) bf16 As[128 * 32];
  __shared__ __align__(16) bf16 Bs[128 * 32];
  const int tid  = threadIdx.x;
  const int wave = tid >> 6, lane = tid & 63;
  const int lr = lane & 15, lq = lane >> 4;
  const int m0 = blockIdx.y * 128, n0 = blockIdx.x * 128;
  const int wm = (wave & 1) * 64, wn = (wave >> 1) * 64;

  f32x4 acc[4][4];
#pragma unroll
  for (int i = 0; i < 4; ++i)
#pragma unroll
    for (int j = 0; j < 4; ++j)
#pragma unroll
      for (int r = 0; r < 4; ++r) acc[i][j][r] = 0.0f;

  const bf16* Ab = A  + (long)m0 * K;
  const bf16* Bb = Bw + (long)n0 * K;
  const int row0 = tid >> 2;            // 0..63
  const int kp0  = (tid & 3) << 3;      // k element offset (0,8,16,24)

  for (int k0 = 0; k0 < K; k0 += 32) {
    __syncthreads();
    gl_lds16(Ab + (long)row0 * K + k0 + kp0,        ((char*)As) + tid * 16);
    gl_lds16(Bb + (long)row0 * K + k0 + kp0,        ((char*)Bs) + tid * 16);
    gl_lds16(Ab + (long)(row0 + 64) * K + k0 + kp0, ((char*)As) + (tid + 256) * 16);
    gl_lds16(Bb + (long)(row0 + 64) * K + k0 + kp0, ((char*)Bs) + (tid + 256) * 16);
    __syncthreads();

    bf16x8 af[4], bfr[4];
#pragma unroll
    for (int i = 0; i < 4; ++i)
      af[i] = *reinterpret_cast<const bf16x8*>(&As[(wm + i * 16 + lr) * 32 + lq * 8]);
#pragma unroll
    for (int j = 0; j < 4; ++j)
      bfr[j] = *reinterpret_cast<const bf16x8*>(&Bs[(wn + j * 16 + lr) * 32 + lq * 8]);
#pragma unroll
    for (int i = 0; i < 4; ++i)
#pragma unroll
      for (int j = 0; j < 4; ++j)
        acc[i][j] = __builtin_amdgcn_mfma_f32_16x16x32_bf16(af[i], bfr[j], acc[i][j], 0, 0, 0);
  }

  // C/D layout: col=lane&15, row=(lane>>4)*4+reg  [m89-verified]
#pragma unroll
  for (int i = 0; i < 4; ++i) {
#pragma unroll
    for (int j = 0; j < 4; ++j) {
#pragma unroll
      for (int r = 0; r < 4; ++r) {
        const int row = m0 + wm + i * 16 + lq * 4 + r;
        const int col = n0 + wn + j * 16 + lr;
        const long idx = (long)row * N + col;
        float v = acc[i][j][r];
        if constexpr (EPI == EPI_BF16) {
          outb[idx] = f2b(v);
        } else if constexpr (EPI == EPI_OM) {
          // om = 1 - a = -expm1(8 * sigmoid(v+ba) * log_sigmoid(lambda))
          // stored instead of a: near a~1, (1-a) keeps full bf16 relative precision
          float rr = sigm(v + biasf[col]);
          float ls = -log1pf(expf(-vecf[col]));
          outb[idx] = f2b(-expm1f(8.0f * rr * ls));
        } else if constexpr (EPI == EPI_U) {
          // gate = sqrt(clip((1-a)(1+a),1e-6)) = sqrt(clip(om*(2-om),1e-6))
          float ii = sigm(v + biasf[col]);
          float om = b2f(auxb2[idx]);
          float g  = sqrtf(fmaxf(om * (2.0f - om), 1e-6f));
          outb[idx] = f2b(g * ii * b2f(auxb[idx]));   // * b1_conv
        } else if constexpr (EPI == EPI_GELU) {
          outb[idx] = f2b(gelu_f(v));
        } else if constexpr (EPI == EPI_GELU_MUL) {
          float u2 = b2f(outb[idx]);                  // RMW in place (u2 from prior kernel)
          outb[idx] = f2b(gelu_f(v) * u2);
        } else if constexpr (EPI == EPI_X1) {
          outb[idx] = f2b(v + auxf[idx]);             // x1 = rec_out + x_seq (f32 aux, bf16 out)
        } else if constexpr (EPI == EPI_X2) {
          outf[idx] = v + b2f(auxb[idx]);             // x2 = mlp + x1 -> f32 OUTPUT
        }
      }
    }
  }
}

// ---- f32 -> bf16 cast (x4 vectorized) ----
__global__ __launch_bounds__(256)
void cast4_kernel(const float* __restrict__ in, bf16* __restrict__ out, long n4) {
  long i = (long)blockIdx.x * 256 + threadIdx.x;
  if (i < n4) {
    float4 v = reinterpret_cast<const float4*>(in)[i];
    union { bf16 h[4]; ushort4 u; } pk;
    pk.h[0] = f2b(v.x); pk.h[1] = f2b(v.y); pk.h[2] = f2b(v.z); pk.h[3] = f2b(v.w);
    reinterpret_cast<ushort4*>(out)[i] = pk.u;
  }
}

// ---- RMSNorm: one block per row (D=1024, 256 thr x 4 elems), f32 weight ----
template <typename TIN>
__global__ __launch_bounds__(256)
void rmsnorm_kernel(const TIN* __restrict__ x, const float* __restrict__ w,
                    bf16* __restrict__ out) {
  const int row = blockIdx.x;
  const int t = threadIdx.x;
  float4 v;
  if constexpr (sizeof(TIN) == 4) {
    v = reinterpret_cast<const float4*>(x + (long)row * ND)[t];
  } else {
    union { ushort4 u; bf16 h[4]; } xv;
    xv.u = reinterpret_cast<const ushort4*>(x + (long)row * ND)[t];
    v = make_float4(b2f(xv.h[0]), b2f(xv.h[1]), b2f(xv.h[2]), b2f(xv.h[3]));
  }
  float ss = v.x * v.x + v.y * v.y + v.z * v.z + v.w * v.w;
#pragma unroll
  for (int off = 32; off > 0; off >>= 1) ss += __shfl_down(ss, off, 64);
  __shared__ float red[4];
  if ((t & 63) == 0) red[t >> 6] = ss;
  __syncthreads();
  float tot = red[0] + red[1] + red[2] + red[3];
  float scale = rsqrtf(tot * (1.0f / ND) + 1.1920929e-07f);
  float4 wv = reinterpret_cast<const float4*>(w)[t];
  union { bf16 h[4]; ushort4 u; } pk;
  pk.h[0] = f2b(v.x * scale * wv.x);
  pk.h[1] = f2b(v.y * scale * wv.y);
  pk.h[2] = f2b(v.z * scale * wv.z);
  pk.h[3] = f2b(v.w * scale * wv.w);
  reinterpret_cast<ushort4*>(out + (long)row * ND)[t] = pk.u;
}

// ---- causal depthwise conv K=4 -> b1_conv (bf16) + new_conv_buf (f32 OUTPUT) ----
__global__ __launch_bounds__(256)
void conv_kernel(const bf16* __restrict__ b1, const float* __restrict__ conv_buf,
                 const float* __restrict__ conv_w, const float* __restrict__ conv_b,
                 bf16* __restrict__ out_b1c, float* __restrict__ out_newbuf) {
  const long gid = (long)blockIdx.x * 256 + threadIdx.x;   // over NM*ND
  const int d = (int)(gid & (ND - 1));
  const long bt = gid >> 10;
  const int t = (int)(bt & (NT_ - 1));
  const int b = (int)(bt >> 10);
  float acc = conv_b[d];
#pragma unroll
  for (int k = 0; k < 4; ++k) {
    const int p = t + k;
    float src = (p < 3) ? conv_buf[((long)b * 3 + p) * ND + d]
                        : b2f(b1[((long)b * NT_ + (p - 3)) * ND + d]);
    acc = fmaf(conv_w[d * 4 + k], src, acc);
  }
  out_b1c[gid] = f2b(acc);
  if (t >= NT_ - 3)
    out_newbuf[((long)b * 3 + (t - (NT_ - 3))) * ND + d] = b2f(b1[gid]);
}

// ---- sequential scan over T (f32 state, om-form), fused with b2 product ----
__global__ __launch_bounds__(256)
void scan_kernel(const bf16* __restrict__ om, const bf16* __restrict__ u,
                 const bf16* __restrict__ b2, const float* __restrict__ h0,
                 bf16* __restrict__ prod, float* __restrict__ newh) {
  const int gid = blockIdx.x * 256 + threadIdx.x;  // NB*ND = 16384 chains
  const int d = gid & (ND - 1);
  const int b = gid >> 10;
  float h = h0[gid];
  const long base = (long)b * NT_ * ND + d;
#pragma unroll 8
  for (int t = 0; t < NT_; ++t) {
    const long idx = base + (long)t * ND;
    // h = a*h + u = h - om*h + u
    h = fmaf(-b2f(om[idx]), h, h) + b2f(u[idx]);
    prod[idx] = f2b(h * b2f(b2[idx]));
  }
  newh[gid] = h;   // f32 OUTPUT
}

// ---- launcher ----
extern "C" void kernel_launch(void* const* d_in, const int* in_sizes, int n_in,
                              void* d_out, int out_size, void* d_ws, size_t ws_size,
                              hipStream_t stream) {
  const float* x_seq    = (const float*)d_in[0];
  const float* h0       = (const float*)d_in[1];
  const float* conv_buf = (const float*)d_in[2];
  const float* norm1_w  = (const float*)d_in[3];
  const float* W1       = (const float*)d_in[4];
  const float* conv_w   = (const float*)d_in[5];
  const float* conv_b   = (const float*)d_in[6];
  const float* Wa       = (const float*)d_in[7];
  const float* ba       = (const float*)d_in[8];
  const float* Wx       = (const float*)d_in[9];
  const float* bx       = (const float*)d_in[10];
  const float* loglam   = (const float*)d_in[11];
  const float* W2       = (const float*)d_in[12];
  const float* Wout     = (const float*)d_in[13];
  const float* norm2_w  = (const float*)d_in[14];
  const float* Wg       = (const float*)d_in[15];
  const float* Wu       = (const float*)d_in[16];
  const float* Wo       = (const float*)d_in[17];

  // ---- workspace arena: exactly 224 MiB (proven-safe in rounds 2/3) ----
  // [0,32M)    normed -> n2                       (K1-K6, K9-K11)
  // [32,64M)   b1 (K2-K3) -> prod (K7-K8)     \
  // [64,96M)   b1_conv (K3-K5) -> Woutb (K8)   |  big 128M overlay (K10-K12)
  // [96,128M)  om bf16 (K4-K7)                 |
  // [128,160M) u bf16 (K5-K7)                 /
  // [160,192M) b2 (K6-K7) -> x1 bf16 (K8-K12)
  // [192,200M) W1b,Wab,Wxb,W2b (2M each)
  // [200,224M) Wgb,Wub,Wob (8M each)
  char* ws = (char*)d_ws;
  bf16* normed = (bf16*)(ws);
  bf16* b1buf  = (bf16*)(ws + (32L  << 20));   // b1, then prod
  bf16* b1cbuf = (bf16*)(ws + (64L  << 20));   // b1_conv
  bf16* Woutb  = (bf16*)(ws + (64L  << 20));   // overlay after b1_conv dies
  bf16* ombuf  = (bf16*)(ws + (96L  << 20));   // om = 1-a
  bf16* ubuf   = (bf16*)(ws + (128L << 20));   // u
  bf16* x1buf  = (bf16*)(ws + (160L << 20));   // b2, then x1
  bf16* b2buf  = x1buf;
  bf16* bigbuf = (bf16*)(ws + (32L  << 20));   // 128M overlay
  bf16* W1b    = (bf16*)(ws + (192L << 20));
  bf16* Wab    = (bf16*)(ws + (194L << 20));
  bf16* Wxb    = (bf16*)(ws + (196L << 20));
  bf16* W2b    = (bf16*)(ws + (198L << 20));
  bf16* Wgb    = (bf16*)(ws + (200L << 20));
  bf16* Wub    = (bf16*)(ws + (208L << 20));
  bf16* Wob    = (bf16*)(ws + (216L << 20));

  float* out_x2 = (float*)d_out;                 // (B,T,D) f32
  float* out_h  = out_x2 + (long)NM * ND;        // (B,D)   f32
  float* out_cb = out_h + NB * ND;               // (B,3,D) f32

  const dim3 blk(256);
  const dim3 gD(ND / 128, NM / 128);   // (8,128)
  const dim3 gH(NH / 128, NM / 128);   // (32,128)

  // upfront weight casts (Wout deferred: its slot holds b1_conv until K5)
  cast4_kernel<<<dim3(1024), blk, 0, stream>>>(W1, W1b, 262144);
  cast4_kernel<<<dim3(1024), blk, 0, stream>>>(Wa, Wab, 262144);
  cast4_kernel<<<dim3(1024), blk, 0, stream>>>(Wx, Wxb, 262144);
  cast4_kernel<<<dim3(1024), blk, 0, stream>>>(W2, W2b, 262144);
  cast4_kernel<<<dim3(4096), blk, 0, stream>>>(Wg, Wgb, 1048576);
  cast4_kernel<<<dim3(4096), blk, 0, stream>>>(Wu, Wub, 1048576);
  cast4_kernel<<<dim3(4096), blk, 0, stream>>>(Wo, Wob, 1048576);

  // K1: normed = rmsnorm(x_seq, norm1_w)
  rmsnorm_kernel<float><<<dim3(NM), blk, 0, stream>>>(x_seq, norm1_w, normed);
  // K2: b1 = normed @ W1^T
  gemm_nt<EPI_BF16><<<gD, blk, 0, stream>>>(normed, W1b, NM, ND, ND,
      nullptr, nullptr, nullptr, nullptr, nullptr, nullptr, b1buf);
  // K3: causal conv -> b1_conv, new_conv_buf (f32 out)
  conv_kernel<<<dim3((NM * ND) / 256), blk, 0, stream>>>(b1buf, conv_buf, conv_w, conv_b,
      b1cbuf, out_cb);
  // K4: om = 1 - exp(8*sigmoid(b1c@Wa^T+ba)*logsig(lam))
  gemm_nt<EPI_OM><<<gD, blk, 0, stream>>>(b1cbuf, Wab, NM, ND, ND,
      ba, loglam, nullptr, nullptr, nullptr, nullptr, ombuf);
  // K5: u = gate(om) * sigmoid(b1c@Wx^T+bx) * b1c
  gemm_nt<EPI_U><<<gD, blk, 0, stream>>>(b1cbuf, Wxb, NM, ND, ND,
      bx, nullptr, b1cbuf, ombuf, nullptr, nullptr, ubuf);
  // K6: b2 = gelu(normed @ W2^T)
  gemm_nt<EPI_GELU><<<gD, blk, 0, stream>>>(normed, W2b, NM, ND, ND,
      nullptr, nullptr, nullptr, nullptr, nullptr, nullptr, b2buf);
  // K7: scan; prod = h*b2 (into b1 slot), new_h (f32 out)
  scan_kernel<<<dim3(NB * ND / 256), blk, 0, stream>>>(ombuf, ubuf, b2buf, h0, b1buf, out_h);
  // late cast: Wout into b1_conv's dead slot
  cast4_kernel<<<dim3(1024), blk, 0, stream>>>(Wout, Woutb, 262144);
  // K8: x1 = x_seq + prod @ Wout^T  (bf16, into b2's dead slot)
  gemm_nt<EPI_X1><<<gD, blk, 0, stream>>>(b1buf, Woutb, NM, ND, ND,
      nullptr, nullptr, nullptr, nullptr, x_seq, nullptr, x1buf);
  // K9: n2 = rmsnorm(x1, norm2_w)
  rmsnorm_kernel<bf16><<<dim3(NM), blk, 0, stream>>>(x1buf, norm2_w, normed);
  // K10: u2 = n2 @ Wu^T -> big
  gemm_nt<EPI_BF16><<<gH, blk, 0, stream>>>(normed, Wub, NM, NH, ND,
      nullptr, nullptr, nullptr, nullptr, nullptr, nullptr, bigbuf);
  // K11: big = gelu(n2 @ Wg^T) * big  (in place)
  gemm_nt<EPI_GELU_MUL><<<gH, blk, 0, stream>>>(normed, Wgb, NM, NH, ND,
      nullptr, nullptr, nullptr, nullptr, nullptr, nullptr, bigbuf);
  // K12: x2 = x1 + big @ Wo^T -> d_out (f32)
  gemm_nt<EPI_X2><<<gD, blk, 0, stream>>>(bigbuf, Wob, NM, ND, NH,
      nullptr, nullptr, x1buf, nullptr, nullptr, out_x2, nullptr);
}